// Round 5
// baseline (268.712 us; speedup 1.0000x reference)
//
#include <hip/hip_runtime.h>
#include <hip/hip_bf16.h>

#define NDRUG 846
#define EDIM 256
#define NS 128
#define XOFF (NDRUG * EDIM)             // x region in d_out (gnn1 slot, f32)
#define B2SOFF (2 * NDRUG * EDIM - NS)  // b2sum in tail of x region
#define NLINBLK 14                      // lin_gemm M-tiles of 64
#define NSTATBLK 54                     // bn_stats m-tiles of 16

typedef short s8v __attribute__((ext_vector_type(8)));
typedef __bf16 b8v __attribute__((ext_vector_type(8)));
typedef float f32x4 __attribute__((ext_vector_type(4)));

static __device__ __forceinline__ short bfs(float f) {
  __bf16 h = (__bf16)f;
  return __builtin_bit_cast(short, h);
}

// direct global->LDS 16B (CK-style plain-pointer form; dest = wave base + lane*16)
static __device__ __forceinline__ void glds16(const float* g, float* l) {
  __builtin_amdgcn_global_load_lds((const unsigned int*)g, (unsigned int*)l, 16, 0, 0);
}

template <typename V>
static __device__ __forceinline__ auto mfma_impl(V a, V b, f32x4 c, int)
    -> decltype(__builtin_amdgcn_mfma_f32_16x16x32_bf16(a, b, c, 0, 0, 0)) {
  return __builtin_amdgcn_mfma_f32_16x16x32_bf16(a, b, c, 0, 0, 0);
}
template <typename V>
static __device__ __forceinline__ f32x4 mfma_impl(V a, V b, f32x4 c, long) {
  b8v ab = __builtin_bit_cast(b8v, a);
  b8v bb = __builtin_bit_cast(b8v, b);
  return __builtin_amdgcn_mfma_f32_16x16x32_bf16(ab, bb, c, 0, 0, 0);
}
static __device__ __forceinline__ f32x4 mfma16(s8v a, s8v b, f32x4 c) {
  return mfma_impl(a, b, c, 0);
}

// ---------------- b2 column-sum precompute (block-invariant) ----------------
__global__ __launch_bounds__(64) void b2prep(const float* __restrict__ b2,
                                             float* __restrict__ b2s) {
  const int n = blockIdx.x;
  const int t = threadIdx.x;
  const float4 v4 = *(const float4*)(b2 + n * EDIM + 4 * t);
  float v = v4.x + v4.y + v4.z + v4.w;
#pragma unroll
  for (int off = 1; off < 64; off <<= 1) v += __shfl_xor(v, off);
  if (t == 0) b2s[n] = v;
}

// ---------------- main per-drug kernel ----------------
__global__ __launch_bounds__(512, 4) void gnn_main(
    const int* __restrict__ drug_name,
    const int* __restrict__ adj_tail,
    const int* __restrict__ adj_relation,
    const float* __restrict__ drug_table,
    const float* __restrict__ rela_table,
    const float* __restrict__ ent_table,
    const float* __restrict__ W1,
    const float* __restrict__ b1,
    const float* __restrict__ W2,
    const float* __restrict__ b2s,
    float* __restrict__ ws_we) {
  __shared__ __align__(16) float s_w1[2][32 * EDIM];  // 64KB dbuf W1 kk-tile (f32)
  __shared__ float s_d[EDIM];
  __shared__ int s_tail[NS];
  __shared__ int s_rel[NS];
  __shared__ float s_w2sum[EDIM];
  __shared__ float s_scorep[8][NS];
  __shared__ float s_attn[NS];

  const int b = blockIdx.x;
  const int tid = threadIdx.x;
  const int w = tid >> 6;
  const int l = tid & 63;
  const int g = l >> 4;
  const int lr = l & 15;
  const int rg = tid >> 4;  // W2 rowsum row group (0..31)
  const int lc = tid & 15;  // W2 rowsum col group

  const float* Wp = W1 + (long)b * EDIM * EDIM;
  const float* W2p = W2 + (long)b * EDIM * EDIM;

  // prologue: stage W1 tile 0 (wave w stages rows 8i+w; 1 glds = 1 full row)
#pragma unroll
  for (int i = 0; i < 4; ++i) {
    const int row = 8 * i + w;
    glds16(Wp + row * EDIM + 4 * l, &s_w1[0][row * EDIM]);
  }

  // small stages: 256 d + 128 tail + 128 rel = exactly 512 threads
  if (tid < EDIM) {
    const int dn = drug_name[b];
    s_d[tid] = drug_table[(long)dn * EDIM + tid];
  } else if (tid < EDIM + NS) {
    s_tail[tid - EDIM] = adj_tail[b * NS + (tid - EDIM)];
  } else {
    s_rel[tid - EDIM - NS] = adj_relation[b * NS + (tid - EDIM - NS)];
  }
  __syncthreads();  // drains glds (tile 0 ready) + small stages

  // Fused kk-loop over K in steps of 32:
  //   h1 += dr(recomputed from L2) @ W1(LDS-staged, dbuf)   [MFMA]
  //   w2sum[rows of kk] = row-sums of W2                    [dwordx4 stream]
  f32x4 acc[8][2];
#pragma unroll
  for (int mt = 0; mt < 8; ++mt) {
    acc[mt][0] = (f32x4){0.f, 0.f, 0.f, 0.f};
    acc[mt][1] = (f32x4){0.f, 0.f, 0.f, 0.f};
  }
  const int col0 = 32 * w + lr;

#pragma unroll
  for (int kk = 0; kk < 8; ++kk) {
    const float* cur = s_w1[kk & 1];
    // (a) stage next W1 tile (no VGPR cost; stays in flight through compute)
    if (kk < 7) {
      float* nxt = s_w1[(kk & 1) ^ 1];
      const float* src = Wp + (kk + 1) * 32 * EDIM;
#pragma unroll
      for (int i = 0; i < 4; ++i) {
        const int row = 8 * i + w;
        glds16(src + row * EDIM + 4 * l, &nxt[row * EDIM]);
      }
    }
    // (b) W2 row-sum for rows [32kk, 32kk+32): 16 f32/thread, summed immediately
    {
      const float* q = W2p + (32 * kk + rg) * EDIM + lc * 16;
      const float4 q0 = *(const float4*)q;
      const float4 q1 = *(const float4*)(q + 4);
      const float4 q2 = *(const float4*)(q + 8);
      const float4 q3 = *(const float4*)(q + 12);
      float v = q0.x + q0.y + q0.z + q0.w + q1.x + q1.y + q1.z + q1.w +
                q2.x + q2.y + q2.z + q2.w + q3.x + q3.y + q3.z + q3.w;
#pragma unroll
      for (int off = 1; off < 16; off <<= 1) v += __shfl_xor(v, off);
      if (lc == 0) s_w2sum[32 * kk + rg] = v;
    }
    // (c) compute on tile kk
    const int e0 = 32 * kk + 8 * g;
    float dv[8];
#pragma unroll
    for (int j = 0; j < 8; ++j) dv[j] = s_d[e0 + j];
    s8v bf0, bf1;
#pragma unroll
    for (int j = 0; j < 8; ++j) {
      bf0[j] = bfs(cur[(8 * g + j) * EDIM + col0]);
      bf1[j] = bfs(cur[(8 * g + j) * EDIM + col0 + 16]);
    }
#pragma unroll
    for (int mt = 0; mt < 8; ++mt) {
      const int n = 16 * mt + lr;
      const float* rrow = rela_table + (long)s_rel[n] * EDIM + e0;
      const float4 r0 = *(const float4*)rrow;
      const float4 r1 = *(const float4*)(rrow + 4);
      s8v af;
      af[0] = bfs(r0.x * dv[0]);
      af[1] = bfs(r0.y * dv[1]);
      af[2] = bfs(r0.z * dv[2]);
      af[3] = bfs(r0.w * dv[3]);
      af[4] = bfs(r1.x * dv[4]);
      af[5] = bfs(r1.y * dv[5]);
      af[6] = bfs(r1.z * dv[6]);
      af[7] = bfs(r1.w * dv[7]);
      acc[mt][0] = mfma16(af, bf0, acc[mt][0]);
      acc[mt][1] = mfma16(af, bf1, acc[mt][1]);
    }
    __syncthreads();  // next tile staged+drained; everyone done reading cur
  }

  // score[n] = sum_f relu(h1[n][f]+b1[n][f]) * w2sum[f]
#pragma unroll
  for (int mt = 0; mt < 8; ++mt) {
#pragma unroll
    for (int jj = 0; jj < 4; ++jj) {
      const int n = 16 * mt + 4 * g + jj;
      const int f0 = 32 * w + lr;
      const int f1 = f0 + 16;
      float v = fmaxf(acc[mt][0][jj] + b1[n * EDIM + f0], 0.f) * s_w2sum[f0] +
                fmaxf(acc[mt][1][jj] + b1[n * EDIM + f1], 0.f) * s_w2sum[f1];
#pragma unroll
      for (int off = 1; off < 16; off <<= 1) v += __shfl_xor(v, off);
      if (lr == 0) s_scorep[w][n] = v;
    }
  }
  __syncthreads();

  // softmax over 128 neighbors (wave 0)
  if (w == 0) {
    float v0 = b2s[l], v1 = b2s[l + 64];
#pragma unroll
    for (int ww = 0; ww < 8; ++ww) {
      v0 += s_scorep[ww][l];
      v1 += s_scorep[ww][l + 64];
    }
    float m = fmaxf(v0, v1);
#pragma unroll
    for (int off = 1; off < 64; off <<= 1) m = fmaxf(m, __shfl_xor(m, off));
    const float e0 = expf(v0 - m), e1 = expf(v1 - m);
    float s = e0 + e1;
#pragma unroll
    for (int off = 1; off < 64; off <<= 1) s += __shfl_xor(s, off);
    const float inv = 1.f / s;
    s_attn[l] = e0 * inv;
    s_attn[l + 64] = e1 * inv;
  }
  __syncthreads();

  // weighted_ent[f] = sum_n attn[n] * ent[tail[n]][f]  (float4, 2-way ILP)
  float* s_scratch = (float*)s_w1;  // W1 tiles dead; reuse 8KB
  {
    const int f4 = tid & 63;
    const int ng = tid >> 6;
    float4 a0 = {0.f, 0.f, 0.f, 0.f}, a1 = {0.f, 0.f, 0.f, 0.f};
#pragma unroll
    for (int i = 0; i < 8; ++i) {
      const int n0 = 16 * ng + i;
      const int n1 = n0 + 8;
      const float4 e0 = *(const float4*)(ent_table + (long)s_tail[n0] * EDIM + 4 * f4);
      const float4 e1 = *(const float4*)(ent_table + (long)s_tail[n1] * EDIM + 4 * f4);
      const float t0 = s_attn[n0], t1 = s_attn[n1];
      a0.x += t0 * e0.x; a0.y += t0 * e0.y; a0.z += t0 * e0.z; a0.w += t0 * e0.w;
      a1.x += t1 * e1.x; a1.y += t1 * e1.y; a1.z += t1 * e1.z; a1.w += t1 * e1.w;
    }
    a0.x += a1.x; a0.y += a1.y; a0.z += a1.z; a0.w += a1.w;
    *(float4*)(s_scratch + ng * 256 + 4 * f4) = a0;
  }
  __syncthreads();

  if (tid < EDIM) {
    float v = 0.f;
#pragma unroll
    for (int ng = 0; ng < 8; ++ng) v += s_scratch[ng * 256 + tid];
    ws_we[(long)b * EDIM + tid] = v;
  }
}

// ---------------- linear layer: x = relu([we|d] @ lin_w + lin_b) ----------------
__global__ __launch_bounds__(512, 4) void lin_gemm(
    const float* __restrict__ ws_we,
    const int* __restrict__ drug_name,
    const float* __restrict__ drug_table,
    const float* __restrict__ lin_w,
    const float* __restrict__ lin_b,
    float* __restrict__ x_out) {
  __shared__ __align__(16) unsigned short s_a[64 * 512];  // 64KB bf16 A-tile, swizzled
  const int blk = blockIdx.x;
  const int m0 = 64 * blk;
  const int tid = threadIdx.x;
  const int w = tid >> 6;
  const int l = tid & 63;
  const int g = l >> 4;
  const int lr = l & 15;

  // stage A rows: [we[m] | d[m]] -> bf16, row stride 1024B, swz ^((r&7)<<4)
  {
    const int r = tid >> 3;
    const int qq = tid & 7;
    const int m = m0 + r;
    const bool valid = m < NDRUG;
    const int c0 = 64 * qq;
    const float* src;
    if (qq < 4) {
      src = ws_we + (long)m * EDIM + c0;
    } else {
      const int dn = valid ? drug_name[m] : 0;
      src = drug_table + (long)dn * EDIM + (c0 - EDIM);
    }
    const int swz = (r & 7) << 4;
#pragma unroll
    for (int u = 0; u < 8; ++u) {
      float4 p0 = valid ? *(const float4*)(src + 8 * u) : (float4){0.f, 0.f, 0.f, 0.f};
      float4 p1 = valid ? *(const float4*)(src + 8 * u + 4) : (float4){0.f, 0.f, 0.f, 0.f};
      s8v v;
      v[0] = bfs(p0.x); v[1] = bfs(p0.y); v[2] = bfs(p0.z); v[3] = bfs(p0.w);
      v[4] = bfs(p1.x); v[5] = bfs(p1.y); v[6] = bfs(p1.z); v[7] = bfs(p1.w);
      *(s8v*)((char*)s_a + ((r * 1024 + (c0 + 8 * u) * 2) ^ swz)) = v;
    }
  }
  __syncthreads();

  f32x4 acc[4][2];
#pragma unroll
  for (int mt = 0; mt < 4; ++mt) {
    acc[mt][0] = (f32x4){0.f, 0.f, 0.f, 0.f};
    acc[mt][1] = (f32x4){0.f, 0.f, 0.f, 0.f};
  }
  {
    const int col0 = 32 * w + lr;
    const int swz = (lr & 7) << 4;
#pragma unroll
    for (int kk = 0; kk < 16; ++kk) {
      const float* pk = lin_w + (kk * 32 + 8 * g) * EDIM + col0;
      s8v bf0, bf1;
#pragma unroll
      for (int j = 0; j < 8; ++j) {
        bf0[j] = bfs(pk[j * EDIM]);
        bf1[j] = bfs(pk[j * EDIM + 16]);
      }
      const int kb = (32 * kk + 8 * g) * 2;
#pragma unroll
      for (int mt = 0; mt < 4; ++mt) {
        const int row = 16 * mt + lr;
        s8v af = *(const s8v*)((const char*)s_a + ((row * 1024 + kb) ^ swz));
        acc[mt][0] = mfma16(af, bf0, acc[mt][0]);
        acc[mt][1] = mfma16(af, bf1, acc[mt][1]);
      }
    }
  }

#pragma unroll
  for (int mt = 0; mt < 4; ++mt) {
#pragma unroll
    for (int nt = 0; nt < 2; ++nt) {
      const int f = 32 * w + 16 * nt + lr;
#pragma unroll
      for (int jj = 0; jj < 4; ++jj) {
        const int m = m0 + 16 * mt + 4 * g + jj;
        if (m < NDRUG)
          x_out[(long)m * EDIM + f] = fmaxf(acc[mt][nt][jj] + lin_b[f], 0.f);
      }
    }
  }
}

// ---------------- BN: stats partials / finalize / apply ----------------
__global__ __launch_bounds__(256) void bn_stats(const float* __restrict__ x,
                                                float* __restrict__ part) {
  const int mb = blockIdx.x * 16;
  const int f = threadIdx.x;
  float s = 0.f, ss = 0.f;
#pragma unroll
  for (int i = 0; i < 16; ++i) {
    const int m = mb + i;
    if (m < NDRUG) {
      const float v = x[(long)m * EDIM + f];
      s += v;
      ss += v * v;
    }
  }
  part[blockIdx.x * 512 + f] = s;
  part[blockIdx.x * 512 + 256 + f] = ss;
}

__global__ __launch_bounds__(256) void bn_finalize(const float* __restrict__ part,
                                                   const float* __restrict__ gamma,
                                                   const float* __restrict__ beta,
                                                   float* __restrict__ scsh) {
  const int f = threadIdx.x;
  float s = 0.f, ss = 0.f;
  for (int b = 0; b < NSTATBLK; ++b) {
    s += part[b * 512 + f];
    ss += part[b * 512 + 256 + f];
  }
  const float mean = s * (1.f / NDRUG);
  const float var = ss * (1.f / NDRUG) - mean * mean;
  const float sc = rsqrtf(var + 1e-5f) * gamma[f];
  scsh[f] = sc;
  scsh[EDIM + f] = beta[f] - mean * sc;
}

__global__ __launch_bounds__(512) void bn_apply(const float* __restrict__ x,
                                                const float* __restrict__ scsh,
                                                float* __restrict__ out) {
  const int i = blockIdx.x * 512 + threadIdx.x;
  const int f = i & 255;
  out[i] = x[i] * scsh[f] + scsh[EDIM + f];
}

__global__ void tail_kernel(const float* __restrict__ gnn1, const int* __restrict__ idx,
                            float* __restrict__ out) {
  const int total4 = NDRUG * EDIM / 4;
  const float4* s4 = (const float4*)gnn1;
  float4* d4 = (float4*)(out + XOFF);
  for (int i = blockIdx.x * blockDim.x + threadIdx.x; i < total4;
       i += gridDim.x * blockDim.x)
    d4[i] = s4[i];
  if (blockIdx.x == 0 && threadIdx.x == 0) out[2 * NDRUG * EDIM] = (float)idx[0];
}

extern "C" void kernel_launch(void* const* d_in, const int* in_sizes, int n_in,
                              void* d_out, int out_size, void* d_ws, size_t ws_size,
                              hipStream_t stream) {
  const float* gnn1       = (const float*)d_in[0];
  const int*   idx        = (const int*)d_in[1];
  const int*   drug_name  = (const int*)d_in[2];
  const int*   adj_tail   = (const int*)d_in[3];
  const int*   adj_rel    = (const int*)d_in[4];
  const float* drug_table = (const float*)d_in[5];
  const float* rela_table = (const float*)d_in[6];
  const float* ent_table  = (const float*)d_in[7];
  const float* W1         = (const float*)d_in[8];
  const float* b1         = (const float*)d_in[9];
  const float* W2         = (const float*)d_in[10];
  const float* b2         = (const float*)d_in[11];
  const float* lin_w      = (const float*)d_in[12];
  const float* lin_b      = (const float*)d_in[13];
  const float* bn_g       = (const float*)d_in[14];
  const float* bn_b       = (const float*)d_in[15];

  float* out = (float*)d_out;
  float* x    = out + XOFF;     // [846][256] f32 in gnn1 slot (tail rewrites later)
  float* b2s  = out + B2SOFF;   // 128 f32 (overwritten by lin_gemm's x afterwards)
  float* part = out;            // bn partials in drug_f slot (bn_apply rewrites)
  float* ws_we = (float*)d_ws;  // [846][256] f32
  float* scsh  = (float*)d_ws;  // reuses we region (we dead after lin_gemm)

  b2prep<<<NS, 64, 0, stream>>>(b2, b2s);
  gnn_main<<<NDRUG, 512, 0, stream>>>(drug_name, adj_tail, adj_rel, drug_table,
                                      rela_table, ent_table, W1, b1, W2, b2s,
                                      ws_we);
  lin_gemm<<<NLINBLK, 512, 0, stream>>>(ws_we, drug_name, drug_table, lin_w,
                                        lin_b, x);
  bn_stats<<<NSTATBLK, 256, 0, stream>>>(x, part);
  bn_finalize<<<1, 256, 0, stream>>>(part, bn_g, bn_b, scsh);
  bn_apply<<<(NDRUG * EDIM) / 512, 512, 0, stream>>>(x, scsh, out);
  tail_kernel<<<240, 256, 0, stream>>>(gnn1, idx, out);
}

// Round 6
// 265.053 us; speedup vs baseline: 1.0138x; 1.0138x over previous
//
#include <hip/hip_runtime.h>
#include <hip/hip_bf16.h>

#define NDRUG 846
#define EDIM 256
#define NS 128
#define XOFF (NDRUG * EDIM)             // x region in d_out (gnn1 slot, f32)
#define B2SOFF (2 * NDRUG * EDIM - NS)  // b2sum in tail of x region
#define NLINBLK 14                      // lin_gemm M-tiles of 64
#define NSTATBLK 54                     // bn_stats m-tiles of 16

typedef short s8v __attribute__((ext_vector_type(8)));
typedef __bf16 b8v __attribute__((ext_vector_type(8)));
typedef float f32x4 __attribute__((ext_vector_type(4)));

static __device__ __forceinline__ short bfs(float f) {
  __bf16 h = (__bf16)f;
  return __builtin_bit_cast(short, h);
}

template <typename V>
static __device__ __forceinline__ auto mfma_impl(V a, V b, f32x4 c, int)
    -> decltype(__builtin_amdgcn_mfma_f32_16x16x32_bf16(a, b, c, 0, 0, 0)) {
  return __builtin_amdgcn_mfma_f32_16x16x32_bf16(a, b, c, 0, 0, 0);
}
template <typename V>
static __device__ __forceinline__ f32x4 mfma_impl(V a, V b, f32x4 c, long) {
  b8v ab = __builtin_bit_cast(b8v, a);
  b8v bb = __builtin_bit_cast(b8v, b);
  return __builtin_amdgcn_mfma_f32_16x16x32_bf16(ab, bb, c, 0, 0, 0);
}
static __device__ __forceinline__ f32x4 mfma16(s8v a, s8v b, f32x4 c) {
  return mfma_impl(a, b, c, 0);
}

// ---------------- b2 column-sum precompute (block-invariant) ----------------
__global__ __launch_bounds__(64) void b2prep(const float* __restrict__ b2,
                                             float* __restrict__ b2s) {
  const int n = blockIdx.x;
  const int t = threadIdx.x;
  const float4 v4 = *(const float4*)(b2 + n * EDIM + 4 * t);
  float v = v4.x + v4.y + v4.z + v4.w;
#pragma unroll
  for (int off = 1; off < 64; off <<= 1) v += __shfl_xor(v, off);
  if (t == 0) b2s[n] = v;
}

// ---------------- main per-drug kernel (1024 thr, 1 block/CU) ----------------
__global__ __launch_bounds__(1024, 4) void gnn_main(
    const int* __restrict__ drug_name,
    const int* __restrict__ adj_tail,
    const int* __restrict__ adj_relation,
    const float* __restrict__ drug_table,
    const float* __restrict__ rela_table,
    const float* __restrict__ ent_table,
    const float* __restrict__ W1,
    const float* __restrict__ b1,
    const float* __restrict__ W2,
    const float* __restrict__ b2s,
    float* __restrict__ ws_we) {
  __shared__ __align__(16) float s_w1[2][32 * EDIM];        // 64KB W1 f32 dbuf
  __shared__ __align__(16) unsigned short s_ab[NS * EDIM];  // 64KB dr bf16, swizzled
  __shared__ float s_d[EDIM];
  __shared__ int s_tail[NS];
  __shared__ float s_w2sum[EDIM];
  __shared__ float s_scorep[16][NS];
  __shared__ float s_attn[NS];

  const int b = blockIdx.x;
  const int tid = threadIdx.x;
  const int w = tid >> 6;   // wave 0..15
  const int l = tid & 63;
  const int g = l >> 4;
  const int lr = l & 15;

  const float* Wp = W1 + (long)b * EDIM * EDIM;
  const float* W2p = W2 + (long)b * EDIM * EDIM;

  // W1 stage addressing: tile kt, pass p -> row 16p+w, lane covers dwords [4l,4l+4)
#define W1ADDR(kt, p) (Wp + ((kt)*32 + 16 * (p) + w) * EDIM + 4 * l)

  // (1) issue W1 tiles 0 and 1 into registers FIRST (deepest prefetch)
  float4 ra[2][2];
#pragma unroll
  for (int p = 0; p < 2; ++p) ra[0][p] = *(const float4*)W1ADDR(0, p);
#pragma unroll
  for (int p = 0; p < 2; ++p) ra[1][p] = *(const float4*)W1ADDR(1, p);

  // (2) small stages
  if (tid < EDIM) {
    const int dn = drug_name[b];
    s_d[tid] = drug_table[(long)dn * EDIM + tid];
  } else if (tid < EDIM + NS) {
    s_tail[tid - EDIM] = adj_tail[b * NS + (tid - EDIM)];
  }
  __syncthreads();  // s_d ready for dr scaling

  // (3) dr[n][e] = d[e] * r[n][e] -> s_ab bf16 (XOR-swizzled)
  {
    const int n = tid >> 3;
    const int e0 = (tid & 7) * 32;
    const int rel = adj_relation[b * NS + n];
    const float* rrow = rela_table + (long)rel * EDIM;
    const int swz = (n & 7) << 4;
#pragma unroll
    for (int c = 0; c < 4; ++c) {
      const int e = e0 + c * 8;
      float4 p0 = *(const float4*)(rrow + e);
      float4 p1 = *(const float4*)(rrow + e + 4);
      s8v v;
      v[0] = bfs(p0.x * s_d[e + 0]);
      v[1] = bfs(p0.y * s_d[e + 1]);
      v[2] = bfs(p0.z * s_d[e + 2]);
      v[3] = bfs(p0.w * s_d[e + 3]);
      v[4] = bfs(p1.x * s_d[e + 4]);
      v[5] = bfs(p1.y * s_d[e + 5]);
      v[6] = bfs(p1.z * s_d[e + 6]);
      v[7] = bfs(p1.w * s_d[e + 7]);
      *(s8v*)((char*)s_ab + ((n * 512 + e * 2) ^ swz)) = v;
    }
  }

  // (4) commit W1 tile 0 to LDS (vmcnt waits only tile-0 loads: oldest in queue)
#pragma unroll
  for (int p = 0; p < 2; ++p)
    *(float4*)&s_w1[0][(16 * p + w) * EDIM + 4 * l] = ra[0][p];
  __syncthreads();  // dr tile + W1 buf0 ready

  // kk-loop: h1 += dr @ W1 (LDS dbuf, reg round-trip depth-2) + fused W2 rowsum
  f32x4 acc[8];
#pragma unroll
  for (int mt = 0; mt < 8; ++mt) acc[mt] = (f32x4){0.f, 0.f, 0.f, 0.f};
  const int col0 = 16 * w + lr;  // wave owns cols [16w,16w+16)
  const int swzf = (lr & 7) << 4;
  const int rw = tid >> 5;        // W2 row group 0..31
  const int cw = (tid & 31) * 8;  // W2 col base

#pragma unroll
  for (int kk = 0; kk < 8; ++kk) {
    // (a) issue loads for tile kk+2 (reuse the reg set whose tile is now in LDS)
    if (kk < 6) {
#pragma unroll
      for (int p = 0; p < 2; ++p) ra[kk & 1][p] = *(const float4*)W1ADDR(kk + 2, p);
    }
    // (b) W2 row-sum rows [32kk,32kk+32): 2 fat loads, immediate 32-lane reduce
    {
      const float* q = W2p + (32 * kk + rw) * EDIM + cw;
      const float4 q0 = *(const float4*)q;
      const float4 q1 = *(const float4*)(q + 4);
      float v = q0.x + q0.y + q0.z + q0.w + q1.x + q1.y + q1.z + q1.w;
#pragma unroll
      for (int off = 1; off < 32; off <<= 1) v += __shfl_xor(v, off);
      if ((tid & 31) == 0) s_w2sum[32 * kk + rw] = v;
    }
    // (c) MFMA on current LDS tile
    {
      const float* curw = s_w1[kk & 1];
      s8v bf0;
#pragma unroll
      for (int j = 0; j < 8; ++j) bf0[j] = bfs(curw[(8 * g + j) * EDIM + col0]);
      const int kb = (32 * kk + 8 * g) * 2;
#pragma unroll
      for (int mt = 0; mt < 8; ++mt) {
        const int row = 16 * mt + lr;
        s8v af = *(const s8v*)((const char*)s_ab + ((row * 512 + kb) ^ swzf));
        acc[mt] = mfma16(af, bf0, acc[mt]);
      }
    }
    // (d) commit tile kk+1 (its loads are one full iteration old -> hidden)
    if (kk < 7) {
      float* nb = s_w1[(kk + 1) & 1];
#pragma unroll
      for (int p = 0; p < 2; ++p)
        *(float4*)&nb[(16 * p + w) * EDIM + 4 * l] = ra[(kk + 1) & 1][p];
    }
    __syncthreads();
  }
#undef W1ADDR

  // score[n] = sum_f relu(h1[n][f]+b1[n][f]) * w2sum[f]; 16 wave-partials
#pragma unroll
  for (int mt = 0; mt < 8; ++mt) {
#pragma unroll
    for (int jj = 0; jj < 4; ++jj) {
      const int n = 16 * mt + 4 * g + jj;
      float v = fmaxf(acc[mt][jj] + b1[n * EDIM + col0], 0.f) * s_w2sum[col0];
#pragma unroll
      for (int off = 1; off < 16; off <<= 1) v += __shfl_xor(v, off);
      if (lr == 0) s_scorep[w][n] = v;
    }
  }
  __syncthreads();

  // softmax over 128 neighbors (wave 0), deterministic 16-term sums
  if (w == 0) {
    float v0 = b2s[l], v1 = b2s[l + 64];
#pragma unroll
    for (int ww = 0; ww < 16; ++ww) {
      v0 += s_scorep[ww][l];
      v1 += s_scorep[ww][l + 64];
    }
    float m = fmaxf(v0, v1);
#pragma unroll
    for (int off = 1; off < 64; off <<= 1) m = fmaxf(m, __shfl_xor(m, off));
    const float e0 = expf(v0 - m), e1 = expf(v1 - m);
    float s = e0 + e1;
#pragma unroll
    for (int off = 1; off < 64; off <<= 1) s += __shfl_xor(s, off);
    const float inv = 1.f / s;
    s_attn[l] = e0 * inv;
    s_attn[l + 64] = e1 * inv;
  }
  __syncthreads();

  // weighted_ent[f] = sum_n attn[n] * ent[tail[n]][f]  (float4, 16 n-groups)
  float* s_scratch = (float*)s_w1;  // W1 tiles dead; reuse 16KB
  {
    const int f4 = tid & 63;
    const int ng = tid >> 6;  // 0..15, neighbors [8ng, 8ng+8)
    float4 a0 = {0.f, 0.f, 0.f, 0.f}, a1 = {0.f, 0.f, 0.f, 0.f};
#pragma unroll
    for (int i = 0; i < 4; ++i) {
      const int n0 = 8 * ng + i;
      const int n1 = n0 + 4;
      const float4 e0 = *(const float4*)(ent_table + (long)s_tail[n0] * EDIM + 4 * f4);
      const float4 e1 = *(const float4*)(ent_table + (long)s_tail[n1] * EDIM + 4 * f4);
      const float t0 = s_attn[n0], t1 = s_attn[n1];
      a0.x += t0 * e0.x; a0.y += t0 * e0.y; a0.z += t0 * e0.z; a0.w += t0 * e0.w;
      a1.x += t1 * e1.x; a1.y += t1 * e1.y; a1.z += t1 * e1.z; a1.w += t1 * e1.w;
    }
    a0.x += a1.x; a0.y += a1.y; a0.z += a1.z; a0.w += a1.w;
    *(float4*)(s_scratch + ng * 256 + 4 * f4) = a0;
  }
  __syncthreads();

  if (tid < EDIM) {
    float v = 0.f;
#pragma unroll
    for (int ng = 0; ng < 16; ++ng) v += s_scratch[ng * 256 + tid];
    ws_we[(long)b * EDIM + tid] = v;
  }
}

// ---------------- linear layer: x = relu([we|d] @ lin_w + lin_b) ----------------
__global__ __launch_bounds__(512, 4) void lin_gemm(
    const float* __restrict__ ws_we,
    const int* __restrict__ drug_name,
    const float* __restrict__ drug_table,
    const float* __restrict__ lin_w,
    const float* __restrict__ lin_b,
    float* __restrict__ x_out) {
  __shared__ __align__(16) unsigned short s_a[64 * 512];  // 64KB bf16 A-tile, swizzled
  const int blk = blockIdx.x;
  const int m0 = 64 * blk;
  const int tid = threadIdx.x;
  const int w = tid >> 6;
  const int l = tid & 63;
  const int g = l >> 4;
  const int lr = l & 15;

  {
    const int r = tid >> 3;
    const int qq = tid & 7;
    const int m = m0 + r;
    const bool valid = m < NDRUG;
    const int c0 = 64 * qq;
    const float* src;
    if (qq < 4) {
      src = ws_we + (long)m * EDIM + c0;
    } else {
      const int dn = valid ? drug_name[m] : 0;
      src = drug_table + (long)dn * EDIM + (c0 - EDIM);
    }
    const int swz = (r & 7) << 4;
#pragma unroll
    for (int u = 0; u < 8; ++u) {
      float4 p0 = valid ? *(const float4*)(src + 8 * u) : (float4){0.f, 0.f, 0.f, 0.f};
      float4 p1 = valid ? *(const float4*)(src + 8 * u + 4) : (float4){0.f, 0.f, 0.f, 0.f};
      s8v v;
      v[0] = bfs(p0.x); v[1] = bfs(p0.y); v[2] = bfs(p0.z); v[3] = bfs(p0.w);
      v[4] = bfs(p1.x); v[5] = bfs(p1.y); v[6] = bfs(p1.z); v[7] = bfs(p1.w);
      *(s8v*)((char*)s_a + ((r * 1024 + (c0 + 8 * u) * 2) ^ swz)) = v;
    }
  }
  __syncthreads();

  f32x4 acc[4][2];
#pragma unroll
  for (int mt = 0; mt < 4; ++mt) {
    acc[mt][0] = (f32x4){0.f, 0.f, 0.f, 0.f};
    acc[mt][1] = (f32x4){0.f, 0.f, 0.f, 0.f};
  }
  {
    const int col0 = 32 * w + lr;
    const int swz = (lr & 7) << 4;
#pragma unroll
    for (int kk = 0; kk < 16; ++kk) {
      const float* pk = lin_w + (kk * 32 + 8 * g) * EDIM + col0;
      s8v bf0, bf1;
#pragma unroll
      for (int j = 0; j < 8; ++j) {
        bf0[j] = bfs(pk[j * EDIM]);
        bf1[j] = bfs(pk[j * EDIM + 16]);
      }
      const int kb = (32 * kk + 8 * g) * 2;
#pragma unroll
      for (int mt = 0; mt < 4; ++mt) {
        const int row = 16 * mt + lr;
        s8v af = *(const s8v*)((const char*)s_a + ((row * 1024 + kb) ^ swz));
        acc[mt][0] = mfma16(af, bf0, acc[mt][0]);
        acc[mt][1] = mfma16(af, bf1, acc[mt][1]);
      }
    }
  }

#pragma unroll
  for (int mt = 0; mt < 4; ++mt) {
#pragma unroll
    for (int nt = 0; nt < 2; ++nt) {
      const int f = 32 * w + 16 * nt + lr;
#pragma unroll
      for (int jj = 0; jj < 4; ++jj) {
        const int m = m0 + 16 * mt + 4 * g + jj;
        if (m < NDRUG)
          x_out[(long)m * EDIM + f] = fmaxf(acc[mt][nt][jj] + lin_b[f], 0.f);
      }
    }
  }
}

// ---------------- BN: stats partials / finalize / apply ----------------
__global__ __launch_bounds__(256) void bn_stats(const float* __restrict__ x,
                                                float* __restrict__ part) {
  const int mb = blockIdx.x * 16;
  const int f = threadIdx.x;
  float s = 0.f, ss = 0.f;
#pragma unroll
  for (int i = 0; i < 16; ++i) {
    const int m = mb + i;
    if (m < NDRUG) {
      const float v = x[(long)m * EDIM + f];
      s += v;
      ss += v * v;
    }
  }
  part[blockIdx.x * 512 + f] = s;
  part[blockIdx.x * 512 + 256 + f] = ss;
}

__global__ __launch_bounds__(256) void bn_finalize(const float* __restrict__ part,
                                                   const float* __restrict__ gamma,
                                                   const float* __restrict__ beta,
                                                   float* __restrict__ scsh) {
  const int f = threadIdx.x;
  float s = 0.f, ss = 0.f;
  for (int b = 0; b < NSTATBLK; ++b) {
    s += part[b * 512 + f];
    ss += part[b * 512 + 256 + f];
  }
  const float mean = s * (1.f / NDRUG);
  const float var = ss * (1.f / NDRUG) - mean * mean;
  const float sc = rsqrtf(var + 1e-5f) * gamma[f];
  scsh[f] = sc;
  scsh[EDIM + f] = beta[f] - mean * sc;
}

__global__ __launch_bounds__(512) void bn_apply(const float* __restrict__ x,
                                                const float* __restrict__ scsh,
                                                float* __restrict__ out) {
  const int i = blockIdx.x * 512 + threadIdx.x;
  const int f = i & 255;
  out[i] = x[i] * scsh[f] + scsh[EDIM + f];
}

__global__ void tail_kernel(const float* __restrict__ gnn1, const int* __restrict__ idx,
                            float* __restrict__ out) {
  const int total4 = NDRUG * EDIM / 4;
  const float4* s4 = (const float4*)gnn1;
  float4* d4 = (float4*)(out + XOFF);
  for (int i = blockIdx.x * blockDim.x + threadIdx.x; i < total4;
       i += gridDim.x * blockDim.x)
    d4[i] = s4[i];
  if (blockIdx.x == 0 && threadIdx.x == 0) out[2 * NDRUG * EDIM] = (float)idx[0];
}

extern "C" void kernel_launch(void* const* d_in, const int* in_sizes, int n_in,
                              void* d_out, int out_size, void* d_ws, size_t ws_size,
                              hipStream_t stream) {
  const float* gnn1       = (const float*)d_in[0];
  const int*   idx        = (const int*)d_in[1];
  const int*   drug_name  = (const int*)d_in[2];
  const int*   adj_tail   = (const int*)d_in[3];
  const int*   adj_rel    = (const int*)d_in[4];
  const float* drug_table = (const float*)d_in[5];
  const float* rela_table = (const float*)d_in[6];
  const float* ent_table  = (const float*)d_in[7];
  const float* W1         = (const float*)d_in[8];
  const float* b1         = (const float*)d_in[9];
  const float* W2         = (const float*)d_in[10];
  const float* b2         = (const float*)d_in[11];
  const float* lin_w      = (const float*)d_in[12];
  const float* lin_b      = (const float*)d_in[13];
  const float* bn_g       = (const float*)d_in[14];
  const float* bn_b       = (const float*)d_in[15];

  float* out = (float*)d_out;
  float* x    = out + XOFF;     // [846][256] f32 in gnn1 slot (tail rewrites later)
  float* b2s  = out + B2SOFF;   // 128 f32 (overwritten by lin_gemm's x afterwards)
  float* part = out;            // bn partials in drug_f slot (bn_apply rewrites)
  float* ws_we = (float*)d_ws;  // [846][256] f32
  float* scsh  = (float*)d_ws;  // reuses we region (we dead after lin_gemm)

  b2prep<<<NS, 64, 0, stream>>>(b2, b2s);
  gnn_main<<<NDRUG, 1024, 0, stream>>>(drug_name, adj_tail, adj_rel, drug_table,
                                       rela_table, ent_table, W1, b1, W2, b2s,
                                       ws_we);
  lin_gemm<<<NLINBLK, 512, 0, stream>>>(ws_we, drug_name, drug_table, lin_w,
                                        lin_b, x);
  bn_stats<<<NSTATBLK, 256, 0, stream>>>(x, part);
  bn_finalize<<<1, 256, 0, stream>>>(part, bn_g, bn_b, scsh);
  bn_apply<<<(NDRUG * EDIM) / 512, 512, 0, stream>>>(x, scsh, out);
  tail_kernel<<<240, 256, 0, stream>>>(gnn1, idx, out);
}

// Round 7
// 225.533 us; speedup vs baseline: 1.1915x; 1.1752x over previous
//
#include <hip/hip_runtime.h>
#include <hip/hip_bf16.h>

#define NDRUG 846
#define EDIM 256
#define NS 128
#define XOFF (NDRUG * EDIM)             // x region in d_out (gnn1 slot, f32)
#define B2SOFF (2 * NDRUG * EDIM - NS)  // b2sum in tail of x region
#define NLINBLK 14                      // lin_gemm M-tiles of 64
#define NSTATBLK 54                     // bn_stats m-tiles of 16

typedef short s8v __attribute__((ext_vector_type(8)));
typedef __bf16 b8v __attribute__((ext_vector_type(8)));
typedef float f32x4 __attribute__((ext_vector_type(4)));

static __device__ __forceinline__ short bfs(float f) {
  __bf16 h = (__bf16)f;
  return __builtin_bit_cast(short, h);
}

// direct global->LDS 16B; dest = wave-uniform base + lane*16 (m104 rule)
static __device__ __forceinline__ void glds16(const float* g, float* l) {
  __builtin_amdgcn_global_load_lds((const unsigned int*)g, (unsigned int*)l, 16, 0, 0);
}

template <typename V>
static __device__ __forceinline__ auto mfma_impl(V a, V b, f32x4 c, int)
    -> decltype(__builtin_amdgcn_mfma_f32_16x16x32_bf16(a, b, c, 0, 0, 0)) {
  return __builtin_amdgcn_mfma_f32_16x16x32_bf16(a, b, c, 0, 0, 0);
}
template <typename V>
static __device__ __forceinline__ f32x4 mfma_impl(V a, V b, f32x4 c, long) {
  b8v ab = __builtin_bit_cast(b8v, a);
  b8v bb = __builtin_bit_cast(b8v, b);
  return __builtin_amdgcn_mfma_f32_16x16x32_bf16(ab, bb, c, 0, 0, 0);
}
static __device__ __forceinline__ f32x4 mfma16(s8v a, s8v b, f32x4 c) {
  return mfma_impl(a, b, c, 0);
}

// ---------------- b2 column-sum precompute (block-invariant) ----------------
__global__ __launch_bounds__(64) void b2prep(const float* __restrict__ b2,
                                             float* __restrict__ b2s) {
  const int n = blockIdx.x;
  const int t = threadIdx.x;
  const float4 v4 = *(const float4*)(b2 + n * EDIM + 4 * t);
  float v = v4.x + v4.y + v4.z + v4.w;
#pragma unroll
  for (int off = 1; off < 64; off <<= 1) v += __shfl_xor(v, off);
  if (t == 0) b2s[n] = v;
}

// ---------------- main per-drug kernel: counted-vmcnt glds pipeline ----------------
__global__ __launch_bounds__(512, 2) void gnn_main(
    const int* __restrict__ drug_name,
    const int* __restrict__ adj_tail,
    const int* __restrict__ adj_relation,
    const float* __restrict__ drug_table,
    const float* __restrict__ rela_table,
    const float* __restrict__ ent_table,
    const float* __restrict__ W1,
    const float* __restrict__ b1,
    const float* __restrict__ W2,
    const float* __restrict__ b2s,
    float* __restrict__ ws_we) {
  __shared__ __align__(16) float s_w1[2][32 * EDIM];        // 64KB W1 f32 dbuf (glds dest)
  __shared__ __align__(16) unsigned short s_ab[NS * EDIM];  // 64KB dr bf16, XOR-swizzled
  __shared__ float s_d[EDIM];
  __shared__ int s_tail[NS];
  __shared__ float s_w2sum[EDIM];
  __shared__ float s_scorep[8][NS];
  __shared__ float s_attn[NS];

  const int b = blockIdx.x;
  const int tid = threadIdx.x;
  const int w = tid >> 6;
  const int l = tid & 63;
  const int g = l >> 4;
  const int lr = l & 15;
  const int rg = tid >> 4;  // W2 rowsum row group 0..31
  const int lc = tid & 15;  // W2 rowsum col group

  const float* Wp = W1 + (long)b * EDIM * EDIM;
  const float* W2p = W2 + (long)b * EDIM * EDIM;

  // prologue: stage W1 tile 0 (wave w -> rows 8i+w; one glds = one 1KB row)
#pragma unroll
  for (int i = 0; i < 4; ++i) {
    const int row = 8 * i + w;
    glds16(Wp + row * EDIM + 4 * l, &s_w1[0][row * EDIM]);
  }

  if (tid < EDIM) {
    const int dn = drug_name[b];
    s_d[tid] = drug_table[(long)dn * EDIM + tid];
  } else if (tid < EDIM + NS) {
    s_tail[tid - EDIM] = adj_tail[b * NS + (tid - EDIM)];
  }
  __syncthreads();  // drains glds tile0 + small stages

  // dr[n][e] = d[e] * r[n][e] -> s_ab bf16 (XOR-swizzled)
  {
    const int n = tid >> 2;
    const int e0 = (tid & 3) * 64;
    const int rel = adj_relation[b * NS + n];
    const float* rrow = rela_table + (long)rel * EDIM;
    const int swz = (n & 7) << 4;
#pragma unroll
    for (int c = 0; c < 8; ++c) {
      const int e = e0 + c * 8;
      float4 p0 = *(const float4*)(rrow + e);
      float4 p1 = *(const float4*)(rrow + e + 4);
      s8v v;
      v[0] = bfs(p0.x * s_d[e + 0]);
      v[1] = bfs(p0.y * s_d[e + 1]);
      v[2] = bfs(p0.z * s_d[e + 2]);
      v[3] = bfs(p0.w * s_d[e + 3]);
      v[4] = bfs(p1.x * s_d[e + 4]);
      v[5] = bfs(p1.y * s_d[e + 5]);
      v[6] = bfs(p1.z * s_d[e + 6]);
      v[7] = bfs(p1.w * s_d[e + 7]);
      *(s8v*)((char*)s_ab + ((n * 512 + e * 2) ^ swz)) = v;
    }
  }
  __syncthreads();  // dr ready; vmcnt = 0 entering the loop

  f32x4 acc[8][2];
#pragma unroll
  for (int mt = 0; mt < 8; ++mt) {
    acc[mt][0] = (f32x4){0.f, 0.f, 0.f, 0.f};
    acc[mt][1] = (f32x4){0.f, 0.f, 0.f, 0.f};
  }
  const int col0 = 32 * w + lr;
  const int swzf = (lr & 7) << 4;

  // Per iter (unrolled; all counts compile-time):
  //   b1 | q(W2)x4 | glds(kk+1)x4 | vmcnt(8) [drains glds(kk)+q, keeps glds(kk+1)]
  //   | b2 | reduce q (compiler emits vmcnt(4), glds stay) | MFMA on tile kk
#pragma unroll
  for (int kk = 0; kk < 8; ++kk) {
    __builtin_amdgcn_s_barrier();  // all waves done computing tile kk-1
    __builtin_amdgcn_sched_barrier(0);
    // (a) W2 fat loads for rows [32kk, 32kk+32)
    const float* q = W2p + (32 * kk + rg) * EDIM + lc * 16;
    const float4 q0 = *(const float4*)q;
    const float4 q1 = *(const float4*)(q + 4);
    const float4 q2 = *(const float4*)(q + 8);
    const float4 q3 = *(const float4*)(q + 12);
    __builtin_amdgcn_sched_barrier(0);
    // (b) glds for tile kk+1 into the buffer freed by barrier above
    if (kk < 7) {
      float* nxt = s_w1[(kk + 1) & 1];
      const float* src = Wp + (kk + 1) * 32 * EDIM;
#pragma unroll
      for (int i = 0; i < 4; ++i) {
        const int row = 8 * i + w;
        glds16(src + row * EDIM + 4 * l, &nxt[row * EDIM]);
      }
    }
    __builtin_amdgcn_sched_barrier(0);
    // (c) counted wait: prev tile's glds retired, next tile's stay in flight
    if (kk < 7)
      asm volatile("s_waitcnt vmcnt(8)" ::: "memory");
    else
      asm volatile("s_waitcnt vmcnt(4)" ::: "memory");
    __builtin_amdgcn_sched_barrier(0);
    __builtin_amdgcn_s_barrier();  // tile kk fully resident in LDS
    // (d) W2 reduce (waits only its own 4 loads)
    {
      float v = q0.x + q0.y + q0.z + q0.w + q1.x + q1.y + q1.z + q1.w +
                q2.x + q2.y + q2.z + q2.w + q3.x + q3.y + q3.z + q3.w;
#pragma unroll
      for (int off = 1; off < 16; off <<= 1) v += __shfl_xor(v, off);
      if (lc == 0) s_w2sum[32 * kk + rg] = v;
    }
    // (e) MFMA on tile kk: B-frags from f32 LDS, A-frags from dr tile
    {
      const float* curw = s_w1[kk & 1];
      s8v bf0, bf1;
#pragma unroll
      for (int j = 0; j < 8; ++j) {
        bf0[j] = bfs(curw[(8 * g + j) * EDIM + col0]);
        bf1[j] = bfs(curw[(8 * g + j) * EDIM + col0 + 16]);
      }
      const int kb = (32 * kk + 8 * g) * 2;
#pragma unroll
      for (int mt = 0; mt < 8; ++mt) {
        const int row = 16 * mt + lr;
        s8v af = *(const s8v*)((const char*)s_ab + ((row * 512 + kb) ^ swzf));
        acc[mt][0] = mfma16(af, bf0, acc[mt][0]);
        acc[mt][1] = mfma16(af, bf1, acc[mt][1]);
      }
    }
  }
  __syncthreads();  // s_w2sum complete; loop LDS traffic done

  // score[n] = sum_f relu(h1[n][f]+b1[n][f]) * w2sum[f]
#pragma unroll
  for (int mt = 0; mt < 8; ++mt) {
#pragma unroll
    for (int jj = 0; jj < 4; ++jj) {
      const int n = 16 * mt + 4 * g + jj;
      const int f0 = 32 * w + lr;
      const int f1 = f0 + 16;
      float v = fmaxf(acc[mt][0][jj] + b1[n * EDIM + f0], 0.f) * s_w2sum[f0] +
                fmaxf(acc[mt][1][jj] + b1[n * EDIM + f1], 0.f) * s_w2sum[f1];
#pragma unroll
      for (int off = 1; off < 16; off <<= 1) v += __shfl_xor(v, off);
      if (lr == 0) s_scorep[w][n] = v;
    }
  }
  __syncthreads();

  // softmax over 128 neighbors (wave 0)
  if (w == 0) {
    float v0 = b2s[l], v1 = b2s[l + 64];
#pragma unroll
    for (int ww = 0; ww < 8; ++ww) {
      v0 += s_scorep[ww][l];
      v1 += s_scorep[ww][l + 64];
    }
    float m = fmaxf(v0, v1);
#pragma unroll
    for (int off = 1; off < 64; off <<= 1) m = fmaxf(m, __shfl_xor(m, off));
    const float e0 = expf(v0 - m), e1 = expf(v1 - m);
    float s = e0 + e1;
#pragma unroll
    for (int off = 1; off < 64; off <<= 1) s += __shfl_xor(s, off);
    const float inv = 1.f / s;
    s_attn[l] = e0 * inv;
    s_attn[l + 64] = e1 * inv;
  }
  __syncthreads();

  // weighted_ent[f] = sum_n attn[n] * ent[tail[n]][f]  (float4, 2-way ILP)
  float* s_scratch = (float*)s_w1;  // W1 tiles dead; reuse
  {
    const int f4 = tid & 63;
    const int ng = tid >> 6;
    float4 a0 = {0.f, 0.f, 0.f, 0.f}, a1 = {0.f, 0.f, 0.f, 0.f};
#pragma unroll
    for (int i = 0; i < 8; ++i) {
      const int n0 = 16 * ng + i;
      const int n1 = n0 + 8;
      const float4 e0 = *(const float4*)(ent_table + (long)s_tail[n0] * EDIM + 4 * f4);
      const float4 e1 = *(const float4*)(ent_table + (long)s_tail[n1] * EDIM + 4 * f4);
      const float t0 = s_attn[n0], t1 = s_attn[n1];
      a0.x += t0 * e0.x; a0.y += t0 * e0.y; a0.z += t0 * e0.z; a0.w += t0 * e0.w;
      a1.x += t1 * e1.x; a1.y += t1 * e1.y; a1.z += t1 * e1.z; a1.w += t1 * e1.w;
    }
    a0.x += a1.x; a0.y += a1.y; a0.z += a1.z; a0.w += a1.w;
    *(float4*)(s_scratch + ng * 256 + 4 * f4) = a0;
  }
  __syncthreads();

  if (tid < EDIM) {
    float v = 0.f;
#pragma unroll
    for (int ng = 0; ng < 8; ++ng) v += s_scratch[ng * 256 + tid];
    ws_we[(long)b * EDIM + tid] = v;
  }
}

// ---------------- linear layer: x = relu([we|d] @ lin_w + lin_b) ----------------
__global__ __launch_bounds__(512, 4) void lin_gemm(
    const float* __restrict__ ws_we,
    const int* __restrict__ drug_name,
    const float* __restrict__ drug_table,
    const float* __restrict__ lin_w,
    const float* __restrict__ lin_b,
    float* __restrict__ x_out) {
  __shared__ __align__(16) unsigned short s_a[64 * 512];  // 64KB bf16 A-tile, swizzled
  const int blk = blockIdx.x;
  const int m0 = 64 * blk;
  const int tid = threadIdx.x;
  const int w = tid >> 6;
  const int l = tid & 63;
  const int g = l >> 4;
  const int lr = l & 15;

  {
    const int r = tid >> 3;
    const int qq = tid & 7;
    const int m = m0 + r;
    const bool valid = m < NDRUG;
    const int c0 = 64 * qq;
    const float* src;
    if (qq < 4) {
      src = ws_we + (long)m * EDIM + c0;
    } else {
      const int dn = valid ? drug_name[m] : 0;
      src = drug_table + (long)dn * EDIM + (c0 - EDIM);
    }
    const int swz = (r & 7) << 4;
#pragma unroll
    for (int u = 0; u < 8; ++u) {
      float4 p0 = valid ? *(const float4*)(src + 8 * u) : (float4){0.f, 0.f, 0.f, 0.f};
      float4 p1 = valid ? *(const float4*)(src + 8 * u + 4) : (float4){0.f, 0.f, 0.f, 0.f};
      s8v v;
      v[0] = bfs(p0.x); v[1] = bfs(p0.y); v[2] = bfs(p0.z); v[3] = bfs(p0.w);
      v[4] = bfs(p1.x); v[5] = bfs(p1.y); v[6] = bfs(p1.z); v[7] = bfs(p1.w);
      *(s8v*)((char*)s_a + ((r * 1024 + (c0 + 8 * u) * 2) ^ swz)) = v;
    }
  }
  __syncthreads();

  f32x4 acc[4][2];
#pragma unroll
  for (int mt = 0; mt < 4; ++mt) {
    acc[mt][0] = (f32x4){0.f, 0.f, 0.f, 0.f};
    acc[mt][1] = (f32x4){0.f, 0.f, 0.f, 0.f};
  }
  {
    const int col0 = 32 * w + lr;
    const int swz = (lr & 7) << 4;
#pragma unroll
    for (int kk = 0; kk < 16; ++kk) {
      const float* pk = lin_w + (kk * 32 + 8 * g) * EDIM + col0;
      s8v bf0, bf1;
#pragma unroll
      for (int j = 0; j < 8; ++j) {
        bf0[j] = bfs(pk[j * EDIM]);
        bf1[j] = bfs(pk[j * EDIM + 16]);
      }
      const int kb = (32 * kk + 8 * g) * 2;
#pragma unroll
      for (int mt = 0; mt < 4; ++mt) {
        const int row = 16 * mt + lr;
        s8v af = *(const s8v*)((const char*)s_a + ((row * 1024 + kb) ^ swz));
        acc[mt][0] = mfma16(af, bf0, acc[mt][0]);
        acc[mt][1] = mfma16(af, bf1, acc[mt][1]);
      }
    }
  }

#pragma unroll
  for (int mt = 0; mt < 4; ++mt) {
#pragma unroll
    for (int nt = 0; nt < 2; ++nt) {
      const int f = 32 * w + 16 * nt + lr;
#pragma unroll
      for (int jj = 0; jj < 4; ++jj) {
        const int m = m0 + 16 * mt + 4 * g + jj;
        if (m < NDRUG)
          x_out[(long)m * EDIM + f] = fmaxf(acc[mt][nt][jj] + lin_b[f], 0.f);
      }
    }
  }
}

// ---------------- BN: stats partials / finalize / apply ----------------
__global__ __launch_bounds__(256) void bn_stats(const float* __restrict__ x,
                                                float* __restrict__ part) {
  const int mb = blockIdx.x * 16;
  const int f = threadIdx.x;
  float s = 0.f, ss = 0.f;
#pragma unroll
  for (int i = 0; i < 16; ++i) {
    const int m = mb + i;
    if (m < NDRUG) {
      const float v = x[(long)m * EDIM + f];
      s += v;
      ss += v * v;
    }
  }
  part[blockIdx.x * 512 + f] = s;
  part[blockIdx.x * 512 + 256 + f] = ss;
}

__global__ __launch_bounds__(256) void bn_finalize(const float* __restrict__ part,
                                                   const float* __restrict__ gamma,
                                                   const float* __restrict__ beta,
                                                   float* __restrict__ scsh) {
  const int f = threadIdx.x;
  float s = 0.f, ss = 0.f;
  for (int b = 0; b < NSTATBLK; ++b) {
    s += part[b * 512 + f];
    ss += part[b * 512 + 256 + f];
  }
  const float mean = s * (1.f / NDRUG);
  const float var = ss * (1.f / NDRUG) - mean * mean;
  const float sc = rsqrtf(var + 1e-5f) * gamma[f];
  scsh[f] = sc;
  scsh[EDIM + f] = beta[f] - mean * sc;
}

__global__ __launch_bounds__(512) void bn_apply(const float* __restrict__ x,
                                                const float* __restrict__ scsh,
                                                float* __restrict__ out) {
  const int i = blockIdx.x * 512 + threadIdx.x;
  const int f = i & 255;
  out[i] = x[i] * scsh[f] + scsh[EDIM + f];
}

__global__ void tail_kernel(const float* __restrict__ gnn1, const int* __restrict__ idx,
                            float* __restrict__ out) {
  const int total4 = NDRUG * EDIM / 4;
  const float4* s4 = (const float4*)gnn1;
  float4* d4 = (float4*)(out + XOFF);
  for (int i = blockIdx.x * blockDim.x + threadIdx.x; i < total4;
       i += gridDim.x * blockDim.x)
    d4[i] = s4[i];
  if (blockIdx.x == 0 && threadIdx.x == 0) out[2 * NDRUG * EDIM] = (float)idx[0];
}

extern "C" void kernel_launch(void* const* d_in, const int* in_sizes, int n_in,
                              void* d_out, int out_size, void* d_ws, size_t ws_size,
                              hipStream_t stream) {
  const float* gnn1       = (const float*)d_in[0];
  const int*   idx        = (const int*)d_in[1];
  const int*   drug_name  = (const int*)d_in[2];
  const int*   adj_tail   = (const int*)d_in[3];
  const int*   adj_rel    = (const int*)d_in[4];
  const float* drug_table = (const float*)d_in[5];
  const float* rela_table = (const float*)d_in[6];
  const float* ent_table  = (const float*)d_in[7];
  const float* W1         = (const float*)d_in[8];
  const float* b1         = (const float*)d_in[9];
  const float* W2         = (const float*)d_in[10];
  const float* b2         = (const float*)d_in[11];
  const float* lin_w      = (const float*)d_in[12];
  const float* lin_b      = (const float*)d_in[13];
  const float* bn_g       = (const float*)d_in[14];
  const float* bn_b       = (const float*)d_in[15];

  float* out = (float*)d_out;
  float* x    = out + XOFF;     // [846][256] f32 in gnn1 slot (tail rewrites later)
  float* b2s  = out + B2SOFF;   // 128 f32 (overwritten by lin_gemm's x afterwards)
  float* part = out;            // bn partials in drug_f slot (bn_apply rewrites)
  float* ws_we = (float*)d_ws;  // [846][256] f32
  float* scsh  = (float*)d_ws;  // reuses we region (we dead after lin_gemm)

  b2prep<<<NS, 64, 0, stream>>>(b2, b2s);
  gnn_main<<<NDRUG, 512, 0, stream>>>(drug_name, adj_tail, adj_rel, drug_table,
                                      rela_table, ent_table, W1, b1, W2, b2s,
                                      ws_we);
  lin_gemm<<<NLINBLK, 512, 0, stream>>>(ws_we, drug_name, drug_table, lin_w,
                                        lin_b, x);
  bn_stats<<<NSTATBLK, 256, 0, stream>>>(x, part);
  bn_finalize<<<1, 256, 0, stream>>>(part, bn_g, bn_b, scsh);
  bn_apply<<<(NDRUG * EDIM) / 512, 512, 0, stream>>>(x, scsh, out);
  tail_kernel<<<240, 256, 0, stream>>>(gnn1, idx, out);
}

// Round 9
// 220.931 us; speedup vs baseline: 1.2163x; 1.0208x over previous
//
#include <hip/hip_runtime.h>
#include <hip/hip_bf16.h>

#define NDRUG 846
#define EDIM 256
#define NS 128
#define XOFF (NDRUG * EDIM)   // x region in d_out (gnn1 slot, f32)
#define NLINBLK 14            // lin_gemm M-tiles of 64
#define NSTATBLK 54           // bn_stats m-tiles of 16
#define SLABS 4
#define SLABW 64

typedef short s8v __attribute__((ext_vector_type(8)));
typedef __bf16 b8v __attribute__((ext_vector_type(8)));
typedef float f32x4 __attribute__((ext_vector_type(4)));

static __device__ __forceinline__ short bfs(float f) {
  __bf16 h = (__bf16)f;
  return __builtin_bit_cast(short, h);
}

template <typename V>
static __device__ __forceinline__ auto mfma_impl(V a, V b, f32x4 c, int)
    -> decltype(__builtin_amdgcn_mfma_f32_16x16x32_bf16(a, b, c, 0, 0, 0)) {
  return __builtin_amdgcn_mfma_f32_16x16x32_bf16(a, b, c, 0, 0, 0);
}
template <typename V>
static __device__ __forceinline__ f32x4 mfma_impl(V a, V b, f32x4 c, long) {
  b8v ab = __builtin_bit_cast(b8v, a);
  b8v bb = __builtin_bit_cast(b8v, b);
  return __builtin_amdgcn_mfma_f32_16x16x32_bf16(ab, bb, c, 0, 0, 0);
}
static __device__ __forceinline__ f32x4 mfma16(s8v a, s8v b, f32x4 c) {
  return mfma_impl(a, b, c, 0);
}

// ================= kernel A: per-(drug, f-slab) score partials =================
// grid 4*846; block 256 (4 waves). No barriers in the K loop; block-TLP hides HBM.
__global__ __launch_bounds__(256, 4) void score_gemm(
    const int* __restrict__ drug_name,
    const int* __restrict__ adj_relation,
    const float* __restrict__ drug_table,
    const float* __restrict__ rela_table,
    const float* __restrict__ W1,
    const float* __restrict__ b1,
    const float* __restrict__ W2,
    float* __restrict__ scorep) {
  __shared__ float s_d[EDIM];
  __shared__ int s_rel[NS];
  __shared__ float s_w2sum[SLABW];

  const int bid = blockIdx.x;
  const int d = bid % NDRUG;
  const int sl = bid / NDRUG;
  const int f0 = sl * SLABW;
  const int tid = threadIdx.x;
  const int w = tid >> 6;
  const int l = tid & 63;
  const int g = l >> 4;
  const int lr = l & 15;

  const float* W1p = W1 + (long)d * EDIM * EDIM;
  const float* W2p = W2 + (long)d * EDIM * EDIM;

  {
    const int dn = drug_name[d];
    s_d[tid] = drug_table[(long)dn * EDIM + tid];
  }
  if (tid < NS) s_rel[tid] = adj_relation[d * NS + tid];
  __syncthreads();

  // ---- w2sum[e] = sum_F W2[d][e][F] for e in slab (ROW-sum; the algebra's
  //      Σ_F collapse of GEMM2). 4 threads per row, fat dwordx4, shfl-reduce.
  {
    const int r = tid >> 2;         // 0..63: row (f0 + r) of W2
    const int c4 = (tid & 3) * 64;  // this thread's 64-col chunk
    const float* p = W2p + (long)(f0 + r) * EDIM + c4;
    float a = 0.f;
#pragma unroll
    for (int i = 0; i < 16; ++i) {
      const float4 u = *(const float4*)(p + 4 * i);
      a += u.x + u.y + u.z + u.w;
    }
    a += __shfl_xor(a, 1);
    a += __shfl_xor(a, 2);
    if ((tid & 3) == 0) s_w2sum[r] = a;
  }
  __syncthreads();

  // ---- GEMM: wave w owns n-rows [32w,32w+32); cols = slab (64). No barriers. ----
  f32x4 acc[2][4];
#pragma unroll
  for (int mt = 0; mt < 2; ++mt)
#pragma unroll
    for (int nt = 0; nt < 4; ++nt) acc[mt][nt] = (f32x4){0.f, 0.f, 0.f, 0.f};

#pragma unroll
  for (int kk = 0; kk < 8; ++kk) {
    const int e0 = 32 * kk + 8 * g;
    // A-frags from rela_table (L2-resident) * d
    s8v afr[2];
#pragma unroll
    for (int mt = 0; mt < 2; ++mt) {
      const int n = 32 * w + 16 * mt + lr;
      const float* rr = rela_table + (long)s_rel[n] * EDIM + e0;
      const float4 r0 = *(const float4*)rr;
      const float4 r1 = *(const float4*)(rr + 4);
      afr[mt][0] = bfs(r0.x * s_d[e0 + 0]);
      afr[mt][1] = bfs(r0.y * s_d[e0 + 1]);
      afr[mt][2] = bfs(r0.z * s_d[e0 + 2]);
      afr[mt][3] = bfs(r0.w * s_d[e0 + 3]);
      afr[mt][4] = bfs(r1.x * s_d[e0 + 4]);
      afr[mt][5] = bfs(r1.y * s_d[e0 + 5]);
      afr[mt][6] = bfs(r1.z * s_d[e0 + 6]);
      afr[mt][7] = bfs(r1.w * s_d[e0 + 7]);
    }
    // B-frags straight from global W1 (lines fully consumed by the 16 lr lanes)
#pragma unroll
    for (int nt = 0; nt < 4; ++nt) {
      const float* pk = W1p + (long)e0 * EDIM + f0 + 16 * nt + lr;
      s8v bfr;
#pragma unroll
      for (int j = 0; j < 8; ++j) bfr[j] = bfs(pk[j * EDIM]);
      acc[0][nt] = mfma16(afr[0], bfr, acc[0][nt]);
      acc[1][nt] = mfma16(afr[1], bfr, acc[1][nt]);
    }
  }

  // ---- score partial: v[n] = sum_{e in slab} relu(h1+b1)*w2sum[e] ----
#pragma unroll
  for (int mt = 0; mt < 2; ++mt) {
#pragma unroll
    for (int jj = 0; jj < 4; ++jj) {
      const int n = 32 * w + 16 * mt + 4 * g + jj;
      float v = 0.f;
#pragma unroll
      for (int nt = 0; nt < 4; ++nt) {
        const int fc = 16 * nt + lr;
        v += fmaxf(acc[mt][nt][jj] + b1[n * EDIM + f0 + fc], 0.f) * s_w2sum[fc];
      }
#pragma unroll
      for (int off = 1; off < 16; off <<= 1) v += __shfl_xor(v, off);
      if (lr == 0) scorep[((long)sl * NDRUG + d) * NS + n] = v;
    }
  }
}

// ======= kernel B: b2sum + softmax + weighted entity gather -> we =======
__global__ __launch_bounds__(256) void attn_gather(
    const int* __restrict__ adj_tail,
    const float* __restrict__ ent_table,
    const float* __restrict__ b2,
    const float* __restrict__ scorep,
    float* __restrict__ ws_we) {
  __shared__ int s_tail[NS];
  __shared__ float s_sc[NS];
  __shared__ float s_attn[NS];
  __shared__ float s_scr[4][EDIM];

  const int d = blockIdx.x;
  const int tid = threadIdx.x;
  if (tid < NS) s_tail[tid] = adj_tail[d * NS + tid];

  // b2sum partials (b2 is L2/L3-resident, 128KB shared by all blocks)
  {
    const int n = tid & 127;
    const int hh = tid >> 7;
    const float* p = b2 + n * EDIM + hh * 128;
    float bs = 0.f;
#pragma unroll
    for (int i = 0; i < 32; ++i) {
      const float4 u = *(const float4*)(p + 4 * i);
      bs += u.x + u.y + u.z + u.w;
    }
    s_scr[hh][n] = bs;
  }
  __syncthreads();
  if (tid < NS) {
    float v = s_scr[0][tid] + s_scr[1][tid];
#pragma unroll
    for (int sl = 0; sl < SLABS; ++sl)
      v += scorep[((long)sl * NDRUG + d) * NS + tid];
    s_sc[tid] = v;
  }
  __syncthreads();

  if (tid < 64) {
    const float v0 = s_sc[tid], v1 = s_sc[tid + 64];
    float m = fmaxf(v0, v1);
#pragma unroll
    for (int off = 1; off < 64; off <<= 1) m = fmaxf(m, __shfl_xor(m, off));
    const float e0 = expf(v0 - m), e1 = expf(v1 - m);
    float s = e0 + e1;
#pragma unroll
    for (int off = 1; off < 64; off <<= 1) s += __shfl_xor(s, off);
    const float inv = 1.f / s;
    s_attn[tid] = e0 * inv;
    s_attn[tid + 64] = e1 * inv;
  }
  __syncthreads();

  // weighted_ent[f] = sum_n attn[n] * ent[tail[n]][f]
  {
    const int f4 = tid & 63;
    const int ng = tid >> 6;  // neighbors [32ng, 32ng+32)
    float4 a0 = {0.f, 0.f, 0.f, 0.f}, a1 = {0.f, 0.f, 0.f, 0.f};
#pragma unroll
    for (int i = 0; i < 16; ++i) {
      const int n0 = 32 * ng + i;
      const int n1 = n0 + 16;
      const float4 e0v = *(const float4*)(ent_table + (long)s_tail[n0] * EDIM + 4 * f4);
      const float4 e1v = *(const float4*)(ent_table + (long)s_tail[n1] * EDIM + 4 * f4);
      const float t0 = s_attn[n0], t1 = s_attn[n1];
      a0.x += t0 * e0v.x; a0.y += t0 * e0v.y; a0.z += t0 * e0v.z; a0.w += t0 * e0v.w;
      a1.x += t1 * e1v.x; a1.y += t1 * e1v.y; a1.z += t1 * e1v.z; a1.w += t1 * e1v.w;
    }
    a0.x += a1.x; a0.y += a1.y; a0.z += a1.z; a0.w += a1.w;
    *(float4*)(&s_scr[ng][4 * f4]) = a0;
  }
  __syncthreads();
  {
    const float v = s_scr[0][tid] + s_scr[1][tid] + s_scr[2][tid] + s_scr[3][tid];
    ws_we[(long)d * EDIM + tid] = v;
  }
}

// ---------------- linear layer: x = relu([we|d] @ lin_w + lin_b) ----------------
__global__ __launch_bounds__(512, 4) void lin_gemm(
    const float* __restrict__ ws_we,
    const int* __restrict__ drug_name,
    const float* __restrict__ drug_table,
    const float* __restrict__ lin_w,
    const float* __restrict__ lin_b,
    float* __restrict__ x_out) {
  __shared__ __align__(16) unsigned short s_a[64 * 512];  // 64KB bf16 A-tile, swizzled
  const int blk = blockIdx.x;
  const int m0 = 64 * blk;
  const int tid = threadIdx.x;
  const int w = tid >> 6;
  const int l = tid & 63;
  const int g = l >> 4;
  const int lr = l & 15;

  {
    const int r = tid >> 3;
    const int qq = tid & 7;
    const int m = m0 + r;
    const bool valid = m < NDRUG;
    const int c0 = 64 * qq;
    const float* src;
    if (qq < 4) {
      src = ws_we + (long)m * EDIM + c0;
    } else {
      const int dn = valid ? drug_name[m] : 0;
      src = drug_table + (long)dn * EDIM + (c0 - EDIM);
    }
    const int swz = (r & 7) << 4;
#pragma unroll
    for (int u = 0; u < 8; ++u) {
      float4 p0 = valid ? *(const float4*)(src + 8 * u) : (float4){0.f, 0.f, 0.f, 0.f};
      float4 p1 = valid ? *(const float4*)(src + 8 * u + 4) : (float4){0.f, 0.f, 0.f, 0.f};
      s8v v;
      v[0] = bfs(p0.x); v[1] = bfs(p0.y); v[2] = bfs(p0.z); v[3] = bfs(p0.w);
      v[4] = bfs(p1.x); v[5] = bfs(p1.y); v[6] = bfs(p1.z); v[7] = bfs(p1.w);
      *(s8v*)((char*)s_a + ((r * 1024 + (c0 + 8 * u) * 2) ^ swz)) = v;
    }
  }
  __syncthreads();

  f32x4 acc[4][2];
#pragma unroll
  for (int mt = 0; mt < 4; ++mt) {
    acc[mt][0] = (f32x4){0.f, 0.f, 0.f, 0.f};
    acc[mt][1] = (f32x4){0.f, 0.f, 0.f, 0.f};
  }
  {
    const int col0 = 32 * w + lr;
    const int swz = (lr & 7) << 4;
#pragma unroll
    for (int kk = 0; kk < 16; ++kk) {
      const float* pk = lin_w + (kk * 32 + 8 * g) * EDIM + col0;
      s8v bf0, bf1;
#pragma unroll
      for (int j = 0; j < 8; ++j) {
        bf0[j] = bfs(pk[j * EDIM]);
        bf1[j] = bfs(pk[j * EDIM + 16]);
      }
      const int kb = (32 * kk + 8 * g) * 2;
#pragma unroll
      for (int mt = 0; mt < 4; ++mt) {
        const int row = 16 * mt + lr;
        s8v af = *(const s8v*)((const char*)s_a + ((row * 1024 + kb) ^ swz));
        acc[mt][0] = mfma16(af, bf0, acc[mt][0]);
        acc[mt][1] = mfma16(af, bf1, acc[mt][1]);
      }
    }
  }

#pragma unroll
  for (int mt = 0; mt < 4; ++mt) {
#pragma unroll
    for (int nt = 0; nt < 2; ++nt) {
      const int f = 32 * w + 16 * nt + lr;
#pragma unroll
      for (int jj = 0; jj < 4; ++jj) {
        const int m = m0 + 16 * mt + 4 * g + jj;
        if (m < NDRUG)
          x_out[(long)m * EDIM + f] = fmaxf(acc[mt][nt][jj] + lin_b[f], 0.f);
      }
    }
  }
}

// ---------------- BN: stats partials / finalize / apply ----------------
__global__ __launch_bounds__(256) void bn_stats(const float* __restrict__ x,
                                                float* __restrict__ part) {
  const int mb = blockIdx.x * 16;
  const int f = threadIdx.x;
  float s = 0.f, ss = 0.f;
#pragma unroll
  for (int i = 0; i < 16; ++i) {
    const int m = mb + i;
    if (m < NDRUG) {
      const float v = x[(long)m * EDIM + f];
      s += v;
      ss += v * v;
    }
  }
  part[blockIdx.x * 512 + f] = s;
  part[blockIdx.x * 512 + 256 + f] = ss;
}

__global__ __launch_bounds__(256) void bn_finalize(const float* __restrict__ part,
                                                   const float* __restrict__ gamma,
                                                   const float* __restrict__ beta,
                                                   float* __restrict__ scsh) {
  const int f = threadIdx.x;
  float s = 0.f, ss = 0.f;
  for (int b = 0; b < NSTATBLK; ++b) {
    s += part[b * 512 + f];
    ss += part[b * 512 + 256 + f];
  }
  const float mean = s * (1.f / NDRUG);
  const float var = ss * (1.f / NDRUG) - mean * mean;
  const float sc = rsqrtf(var + 1e-5f) * gamma[f];
  scsh[f] = sc;
  scsh[EDIM + f] = beta[f] - mean * sc;
}

__global__ __launch_bounds__(512) void bn_apply(const float* __restrict__ x,
                                                const float* __restrict__ scsh,
                                                float* __restrict__ out) {
  const int i = blockIdx.x * 512 + threadIdx.x;
  const int f = i & 255;
  out[i] = x[i] * scsh[f] + scsh[EDIM + f];
}

__global__ void tail_kernel(const float* __restrict__ gnn1, const int* __restrict__ idx,
                            float* __restrict__ out) {
  const int total4 = NDRUG * EDIM / 4;
  const float4* s4 = (const float4*)gnn1;
  float4* d4 = (float4*)(out + XOFF);
  for (int i = blockIdx.x * blockDim.x + threadIdx.x; i < total4;
       i += gridDim.x * blockDim.x)
    d4[i] = s4[i];
  if (blockIdx.x == 0 && threadIdx.x == 0) out[2 * NDRUG * EDIM] = (float)idx[0];
}

extern "C" void kernel_launch(void* const* d_in, const int* in_sizes, int n_in,
                              void* d_out, int out_size, void* d_ws, size_t ws_size,
                              hipStream_t stream) {
  const float* gnn1       = (const float*)d_in[0];
  const int*   idx        = (const int*)d_in[1];
  const int*   drug_name  = (const int*)d_in[2];
  const int*   adj_tail   = (const int*)d_in[3];
  const int*   adj_rel    = (const int*)d_in[4];
  const float* drug_table = (const float*)d_in[5];
  const float* rela_table = (const float*)d_in[6];
  const float* ent_table  = (const float*)d_in[7];
  const float* W1         = (const float*)d_in[8];
  const float* b1         = (const float*)d_in[9];
  const float* W2         = (const float*)d_in[10];
  const float* b2         = (const float*)d_in[11];
  const float* lin_w      = (const float*)d_in[12];
  const float* lin_b      = (const float*)d_in[13];
  const float* bn_g       = (const float*)d_in[14];
  const float* bn_b       = (const float*)d_in[15];

  float* out = (float*)d_out;
  // Region lifetimes (all scratch fully rewritten every call, stream-ordered):
  //   scorep = out[0 .. 4*846*128)   dead after attn_gather
  //   x      = out + XOFF            written by lin_gemm (scorep dead)
  //   part   = out[0 ..)             written by bn_stats (scorep dead)
  //   we     = d_ws                  dead after lin_gemm
  //   scsh   = d_ws                  written by bn_finalize (we dead)
  float* scorep = out;
  float* x      = out + XOFF;
  float* part   = out;
  float* ws_we  = (float*)d_ws;
  float* scsh   = (float*)d_ws;

  score_gemm<<<SLABS * NDRUG, 256, 0, stream>>>(drug_name, adj_rel, drug_table,
                                                rela_table, W1, b1, W2, scorep);
  attn_gather<<<NDRUG, 256, 0, stream>>>(adj_tail, ent_table, b2, scorep, ws_we);
  lin_gemm<<<NLINBLK, 512, 0, stream>>>(ws_we, drug_name, drug_table, lin_w,
                                        lin_b, x);
  bn_stats<<<NSTATBLK, 256, 0, stream>>>(x, part);
  bn_finalize<<<1, 256, 0, stream>>>(part, bn_g, bn_b, scsh);
  bn_apply<<<(NDRUG * EDIM) / 512, 512, 0, stream>>>(x, scsh, out);
  tail_kernel<<<240, 256, 0, stream>>>(gnn1, idx, out);
}

// Round 10
// 197.082 us; speedup vs baseline: 1.3634x; 1.1210x over previous
//
#include <hip/hip_runtime.h>
#include <hip/hip_bf16.h>

#define NDRUG 846
#define EDIM 256
#define NS 128
#define XOFF (NDRUG * EDIM)   // x region in d_out (gnn1 slot, f32)
#define NLINBLK 14            // lin_gemm M-tiles of 64
#define NSTATBLK 54           // bn_stats m-tiles of 16
#define SLABS 4
#define SLABW 64

typedef short s8v __attribute__((ext_vector_type(8)));
typedef __bf16 b8v __attribute__((ext_vector_type(8)));
typedef float f32x4 __attribute__((ext_vector_type(4)));

static __device__ __forceinline__ short bfs(float f) {
  __bf16 h = (__bf16)f;
  return __builtin_bit_cast(short, h);
}

template <typename V>
static __device__ __forceinline__ auto mfma_impl(V a, V b, f32x4 c, int)
    -> decltype(__builtin_amdgcn_mfma_f32_16x16x32_bf16(a, b, c, 0, 0, 0)) {
  return __builtin_amdgcn_mfma_f32_16x16x32_bf16(a, b, c, 0, 0, 0);
}
template <typename V>
static __device__ __forceinline__ f32x4 mfma_impl(V a, V b, f32x4 c, long) {
  b8v ab = __builtin_bit_cast(b8v, a);
  b8v bb = __builtin_bit_cast(b8v, b);
  return __builtin_amdgcn_mfma_f32_16x16x32_bf16(ab, bb, c, 0, 0, 0);
}
static __device__ __forceinline__ f32x4 mfma16(s8v a, s8v b, f32x4 c) {
  return mfma_impl(a, b, c, 0);
}

// ================= kernel A: per-(drug, f-slab) score partials =================
// grid 4*846; block 256 (4 waves). W1 kk-tile LDS-staged (fat dwordx4, dbuf,
// issue-early/write-late). ~18KB LDS -> 6-8 blocks/CU; block-TLP hides barriers.
__global__ __launch_bounds__(256) void score_gemm(
    const int* __restrict__ drug_name,
    const int* __restrict__ adj_relation,
    const float* __restrict__ drug_table,
    const float* __restrict__ rela_table,
    const float* __restrict__ W1,
    const float* __restrict__ b1,
    const float* __restrict__ W2,
    float* __restrict__ scorep) {
  __shared__ __align__(16) float s_w1[2][32][SLABW];  // 16KB W1 tile dbuf
  __shared__ float s_d[EDIM];
  __shared__ int s_rel[NS];
  __shared__ float s_w2sum[SLABW];

  const int bid = blockIdx.x;
  const int d = bid % NDRUG;
  const int sl = bid / NDRUG;
  const int f0 = sl * SLABW;
  const int tid = threadIdx.x;
  const int w = tid >> 6;
  const int l = tid & 63;
  const int g = l >> 4;
  const int lr = l & 15;
  const int str = tid >> 4;        // stage row 0..15 (and +16)
  const int stc = (tid & 15) * 4;  // stage col (float4)

  const float* W1p = W1 + (long)d * EDIM * EDIM;
  const float* W2p = W2 + (long)d * EDIM * EDIM;

  // issue tile-0 stage loads FIRST (deepest in the queue)
  float4 st0 = *(const float4*)(W1p + (long)str * EDIM + f0 + stc);
  float4 st1 = *(const float4*)(W1p + (long)(str + 16) * EDIM + f0 + stc);

  {
    const int dn = drug_name[d];
    s_d[tid] = drug_table[(long)dn * EDIM + tid];
  }
  if (tid < NS) s_rel[tid] = adj_relation[d * NS + tid];

  // ---- w2sum[e] = sum_F W2[d][e][F] for e in slab (ROW-sum; GEMM2 collapse) ----
  {
    const int r = tid >> 2;         // 0..63: row (f0 + r) of W2
    const int c4 = (tid & 3) * 64;  // 64-col chunk
    const float* p = W2p + (long)(f0 + r) * EDIM + c4;
    float a = 0.f;
#pragma unroll
    for (int i = 0; i < 16; ++i) {
      const float4 u = *(const float4*)(p + 4 * i);
      a += u.x + u.y + u.z + u.w;
    }
    a += __shfl_xor(a, 1);
    a += __shfl_xor(a, 2);
    if ((tid & 3) == 0) s_w2sum[r] = a;
  }
  __syncthreads();  // s_d, s_rel, s_w2sum visible

  // commit tile 0 (compiler waits its two loads via vmcnt)
  *(float4*)&s_w1[0][str][stc] = st0;
  *(float4*)&s_w1[0][str + 16][stc] = st1;
  __syncthreads();

  // ---- GEMM: wave w owns n-rows [32w,32w+32); cols = slab. 1 barrier/kk. ----
  f32x4 acc[2][4];
#pragma unroll
  for (int mt = 0; mt < 2; ++mt)
#pragma unroll
    for (int nt = 0; nt < 4; ++nt) acc[mt][nt] = (f32x4){0.f, 0.f, 0.f, 0.f};

#pragma unroll
  for (int kk = 0; kk < 8; ++kk) {
    // (a) issue stage loads for tile kk+1 (used an entire compute phase later)
    float4 n0, n1;
    if (kk < 7) {
      const float* src = W1p + (long)(32 * (kk + 1)) * EDIM + f0;
      n0 = *(const float4*)(src + (long)str * EDIM + stc);
      n1 = *(const float4*)(src + (long)(str + 16) * EDIM + stc);
    }
    // (b) A-frags from rela_table (L2-resident) * d
    const int e0 = 32 * kk + 8 * g;
    s8v afr[2];
#pragma unroll
    for (int mt = 0; mt < 2; ++mt) {
      const int n = 32 * w + 16 * mt + lr;
      const float* rr = rela_table + (long)s_rel[n] * EDIM + e0;
      const float4 r0 = *(const float4*)rr;
      const float4 r1 = *(const float4*)(rr + 4);
      afr[mt][0] = bfs(r0.x * s_d[e0 + 0]);
      afr[mt][1] = bfs(r0.y * s_d[e0 + 1]);
      afr[mt][2] = bfs(r0.z * s_d[e0 + 2]);
      afr[mt][3] = bfs(r0.w * s_d[e0 + 3]);
      afr[mt][4] = bfs(r1.x * s_d[e0 + 4]);
      afr[mt][5] = bfs(r1.y * s_d[e0 + 5]);
      afr[mt][6] = bfs(r1.z * s_d[e0 + 6]);
      afr[mt][7] = bfs(r1.w * s_d[e0 + 7]);
    }
    // (c) B-frags from LDS tile; MFMA
#pragma unroll
    for (int nt = 0; nt < 4; ++nt) {
      s8v bfr;
#pragma unroll
      for (int j = 0; j < 8; ++j) bfr[j] = bfs(s_w1[kk & 1][8 * g + j][16 * nt + lr]);
      acc[0][nt] = mfma16(afr[0], bfr, acc[0][nt]);
      acc[1][nt] = mfma16(afr[1], bfr, acc[1][nt]);
    }
    // (d) write-late: commit tile kk+1 into the other buffer
    if (kk < 7) {
      *(float4*)&s_w1[(kk + 1) & 1][str][stc] = n0;
      *(float4*)&s_w1[(kk + 1) & 1][str + 16][stc] = n1;
    }
    __syncthreads();
  }

  // ---- score partial: v[n] = sum_{e in slab} relu(h1+b1)*w2sum[e] ----
#pragma unroll
  for (int mt = 0; mt < 2; ++mt) {
#pragma unroll
    for (int jj = 0; jj < 4; ++jj) {
      const int n = 32 * w + 16 * mt + 4 * g + jj;
      float v = 0.f;
#pragma unroll
      for (int nt = 0; nt < 4; ++nt) {
        const int fc = 16 * nt + lr;
        v += fmaxf(acc[mt][nt][jj] + b1[n * EDIM + f0 + fc], 0.f) * s_w2sum[fc];
      }
#pragma unroll
      for (int off = 1; off < 16; off <<= 1) v += __shfl_xor(v, off);
      if (lr == 0) scorep[((long)sl * NDRUG + d) * NS + n] = v;
    }
  }
}

// ======= kernel B: b2sum + softmax + weighted entity gather -> we =======
__global__ __launch_bounds__(256) void attn_gather(
    const int* __restrict__ adj_tail,
    const float* __restrict__ ent_table,
    const float* __restrict__ b2,
    const float* __restrict__ scorep,
    float* __restrict__ ws_we) {
  __shared__ int s_tail[NS];
  __shared__ float s_sc[NS];
  __shared__ float s_attn[NS];
  __shared__ float s_scr[4][EDIM];

  const int d = blockIdx.x;
  const int tid = threadIdx.x;
  if (tid < NS) s_tail[tid] = adj_tail[d * NS + tid];

  // b2sum partials (b2 is L2/L3-resident, 128KB shared by all blocks)
  {
    const int n = tid & 127;
    const int hh = tid >> 7;
    const float* p = b2 + n * EDIM + hh * 128;
    float bs = 0.f;
#pragma unroll
    for (int i = 0; i < 32; ++i) {
      const float4 u = *(const float4*)(p + 4 * i);
      bs += u.x + u.y + u.z + u.w;
    }
    s_scr[hh][n] = bs;
  }
  __syncthreads();
  if (tid < NS) {
    float v = s_scr[0][tid] + s_scr[1][tid];
#pragma unroll
    for (int sl = 0; sl < SLABS; ++sl)
      v += scorep[((long)sl * NDRUG + d) * NS + tid];
    s_sc[tid] = v;
  }
  __syncthreads();

  if (tid < 64) {
    const float v0 = s_sc[tid], v1 = s_sc[tid + 64];
    float m = fmaxf(v0, v1);
#pragma unroll
    for (int off = 1; off < 64; off <<= 1) m = fmaxf(m, __shfl_xor(m, off));
    const float e0 = expf(v0 - m), e1 = expf(v1 - m);
    float s = e0 + e1;
#pragma unroll
    for (int off = 1; off < 64; off <<= 1) s += __shfl_xor(s, off);
    const float inv = 1.f / s;
    s_attn[tid] = e0 * inv;
    s_attn[tid + 64] = e1 * inv;
  }
  __syncthreads();

  // weighted_ent[f] = sum_n attn[n] * ent[tail[n]][f]
  {
    const int f4 = tid & 63;
    const int ng = tid >> 6;  // neighbors [32ng, 32ng+32)
    float4 a0 = {0.f, 0.f, 0.f, 0.f}, a1 = {0.f, 0.f, 0.f, 0.f};
#pragma unroll
    for (int i = 0; i < 16; ++i) {
      const int n0 = 32 * ng + i;
      const int n1 = n0 + 16;
      const float4 e0v = *(const float4*)(ent_table + (long)s_tail[n0] * EDIM + 4 * f4);
      const float4 e1v = *(const float4*)(ent_table + (long)s_tail[n1] * EDIM + 4 * f4);
      const float t0 = s_attn[n0], t1 = s_attn[n1];
      a0.x += t0 * e0v.x; a0.y += t0 * e0v.y; a0.z += t0 * e0v.z; a0.w += t0 * e0v.w;
      a1.x += t1 * e1v.x; a1.y += t1 * e1v.y; a1.z += t1 * e1v.z; a1.w += t1 * e1v.w;
    }
    a0.x += a1.x; a0.y += a1.y; a0.z += a1.z; a0.w += a1.w;
    *(float4*)(&s_scr[ng][4 * f4]) = a0;
  }
  __syncthreads();
  {
    const float v = s_scr[0][tid] + s_scr[1][tid] + s_scr[2][tid] + s_scr[3][tid];
    ws_we[(long)d * EDIM + tid] = v;
  }
}

// ---------------- linear layer: x = relu([we|d] @ lin_w + lin_b) ----------------
__global__ __launch_bounds__(512, 4) void lin_gemm(
    const float* __restrict__ ws_we,
    const int* __restrict__ drug_name,
    const float* __restrict__ drug_table,
    const float* __restrict__ lin_w,
    const float* __restrict__ lin_b,
    float* __restrict__ x_out) {
  __shared__ __align__(16) unsigned short s_a[64 * 512];  // 64KB bf16 A-tile, swizzled
  const int blk = blockIdx.x;
  const int m0 = 64 * blk;
  const int tid = threadIdx.x;
  const int w = tid >> 6;
  const int l = tid & 63;
  const int g = l >> 4;
  const int lr = l & 15;

  {
    const int r = tid >> 3;
    const int qq = tid & 7;
    const int m = m0 + r;
    const bool valid = m < NDRUG;
    const int c0 = 64 * qq;
    const float* src;
    if (qq < 4) {
      src = ws_we + (long)m * EDIM + c0;
    } else {
      const int dn = valid ? drug_name[m] : 0;
      src = drug_table + (long)dn * EDIM + (c0 - EDIM);
    }
    const int swz = (r & 7) << 4;
#pragma unroll
    for (int u = 0; u < 8; ++u) {
      float4 p0 = valid ? *(const float4*)(src + 8 * u) : (float4){0.f, 0.f, 0.f, 0.f};
      float4 p1 = valid ? *(const float4*)(src + 8 * u + 4) : (float4){0.f, 0.f, 0.f, 0.f};
      s8v v;
      v[0] = bfs(p0.x); v[1] = bfs(p0.y); v[2] = bfs(p0.z); v[3] = bfs(p0.w);
      v[4] = bfs(p1.x); v[5] = bfs(p1.y); v[6] = bfs(p1.z); v[7] = bfs(p1.w);
      *(s8v*)((char*)s_a + ((r * 1024 + (c0 + 8 * u) * 2) ^ swz)) = v;
    }
  }
  __syncthreads();

  f32x4 acc[4][2];
#pragma unroll
  for (int mt = 0; mt < 4; ++mt) {
    acc[mt][0] = (f32x4){0.f, 0.f, 0.f, 0.f};
    acc[mt][1] = (f32x4){0.f, 0.f, 0.f, 0.f};
  }
  {
    const int col0 = 32 * w + lr;
    const int swz = (lr & 7) << 4;
#pragma unroll
    for (int kk = 0; kk < 16; ++kk) {
      const float* pk = lin_w + (kk * 32 + 8 * g) * EDIM + col0;
      s8v bf0, bf1;
#pragma unroll
      for (int j = 0; j < 8; ++j) {
        bf0[j] = bfs(pk[j * EDIM]);
        bf1[j] = bfs(pk[j * EDIM + 16]);
      }
      const int kb = (32 * kk + 8 * g) * 2;
#pragma unroll
      for (int mt = 0; mt < 4; ++mt) {
        const int row = 16 * mt + lr;
        s8v af = *(const s8v*)((const char*)s_a + ((row * 1024 + kb) ^ swz));
        acc[mt][0] = mfma16(af, bf0, acc[mt][0]);
        acc[mt][1] = mfma16(af, bf1, acc[mt][1]);
      }
    }
  }

#pragma unroll
  for (int mt = 0; mt < 4; ++mt) {
#pragma unroll
    for (int nt = 0; nt < 2; ++nt) {
      const int f = 32 * w + 16 * nt + lr;
#pragma unroll
      for (int jj = 0; jj < 4; ++jj) {
        const int m = m0 + 16 * mt + 4 * g + jj;
        if (m < NDRUG)
          x_out[(long)m * EDIM + f] = fmaxf(acc[mt][nt][jj] + lin_b[f], 0.f);
      }
    }
  }
}

// ---------------- BN: stats partials / finalize / apply ----------------
__global__ __launch_bounds__(256) void bn_stats(const float* __restrict__ x,
                                                float* __restrict__ part) {
  const int mb = blockIdx.x * 16;
  const int f = threadIdx.x;
  float s = 0.f, ss = 0.f;
#pragma unroll
  for (int i = 0; i < 16; ++i) {
    const int m = mb + i;
    if (m < NDRUG) {
      const float v = x[(long)m * EDIM + f];
      s += v;
      ss += v * v;
    }
  }
  part[blockIdx.x * 512 + f] = s;
  part[blockIdx.x * 512 + 256 + f] = ss;
}

__global__ __launch_bounds__(256) void bn_finalize(const float* __restrict__ part,
                                                   const float* __restrict__ gamma,
                                                   const float* __restrict__ beta,
                                                   float* __restrict__ scsh) {
  const int f = threadIdx.x;
  float s = 0.f, ss = 0.f;
  for (int b = 0; b < NSTATBLK; ++b) {
    s += part[b * 512 + f];
    ss += part[b * 512 + 256 + f];
  }
  const float mean = s * (1.f / NDRUG);
  const float var = ss * (1.f / NDRUG) - mean * mean;
  const float sc = rsqrtf(var + 1e-5f) * gamma[f];
  scsh[f] = sc;
  scsh[EDIM + f] = beta[f] - mean * sc;
}

__global__ __launch_bounds__(512) void bn_apply(const float* __restrict__ x,
                                                const float* __restrict__ scsh,
                                                float* __restrict__ out) {
  const int i = blockIdx.x * 512 + threadIdx.x;
  const int f = i & 255;
  out[i] = x[i] * scsh[f] + scsh[EDIM + f];
}

__global__ void tail_kernel(const float* __restrict__ gnn1, const int* __restrict__ idx,
                            float* __restrict__ out) {
  const int total4 = NDRUG * EDIM / 4;
  const float4* s4 = (const float4*)gnn1;
  float4* d4 = (float4*)(out + XOFF);
  for (int i = blockIdx.x * blockDim.x + threadIdx.x; i < total4;
       i += gridDim.x * blockDim.x)
    d4[i] = s4[i];
  if (blockIdx.x == 0 && threadIdx.x == 0) out[2 * NDRUG * EDIM] = (float)idx[0];
}

extern "C" void kernel_launch(void* const* d_in, const int* in_sizes, int n_in,
                              void* d_out, int out_size, void* d_ws, size_t ws_size,
                              hipStream_t stream) {
  const float* gnn1       = (const float*)d_in[0];
  const int*   idx        = (const int*)d_in[1];
  const int*   drug_name  = (const int*)d_in[2];
  const int*   adj_tail   = (const int*)d_in[3];
  const int*   adj_rel    = (const int*)d_in[4];
  const float* drug_table = (const float*)d_in[5];
  const float* rela_table = (const float*)d_in[6];
  const float* ent_table  = (const float*)d_in[7];
  const float* W1         = (const float*)d_in[8];
  const float* b1         = (const float*)d_in[9];
  const float* W2         = (const float*)d_in[10];
  const float* b2         = (const float*)d_in[11];
  const float* lin_w      = (const float*)d_in[12];
  const float* lin_b      = (const float*)d_in[13];
  const float* bn_g       = (const float*)d_in[14];
  const float* bn_b       = (const float*)d_in[15];

  float* out = (float*)d_out;
  // Region lifetimes (all scratch fully rewritten every call, stream-ordered):
  //   scorep = out[0 .. 4*846*128)   dead after attn_gather
  //   x      = out + XOFF            written by lin_gemm (scorep dead)
  //   part   = out[0 ..)             written by bn_stats (scorep dead)
  //   we     = d_ws                  dead after lin_gemm
  //   scsh   = d_ws                  written by bn_finalize (we dead)
  float* scorep = out;
  float* x      = out + XOFF;
  float* part   = out;
  float* ws_we  = (float*)d_ws;
  float* scsh   = (float*)d_ws;

  score_gemm<<<SLABS * NDRUG, 256, 0, stream>>>(drug_name, adj_rel, drug_table,
                                                rela_table, W1, b1, W2, scorep);
  attn_gather<<<NDRUG, 256, 0, stream>>>(adj_tail, ent_table, b2, scorep, ws_we);
  lin_gemm<<<NLINBLK, 512, 0, stream>>>(ws_we, drug_name, drug_table, lin_w,
                                        lin_b, x);
  bn_stats<<<NSTATBLK, 256, 0, stream>>>(x, part);
  bn_finalize<<<1, 256, 0, stream>>>(part, bn_g, bn_b, scsh);
  bn_apply<<<(NDRUG * EDIM) / 512, 512, 0, stream>>>(x, scsh, out);
  tail_kernel<<<240, 256, 0, stream>>>(gnn1, idx, out);
}